// Round 1
// baseline (11.748 us; speedup 1.0000x reference)
//
#include <hip/hip_runtime.h>

// Fused model kernel for MI355X (gfx950).
//
// Reference collapse: the RNN scan's carry is out = lin2(x_t) + b2, which is
// independent of the previous carry -> only the LAST timestep (s = S-1)
// matters. So we read xs[r, S-1, b, :] only (5 MB instead of 335 MB).
//
// One thread per batch row b:
//   x[0:6]   = x0[b]
//   x[6+2r+o]= xs[r,S-1,b,:] @ rnn_w2[r].T + rnn_b2[r]
//   h1 = relu(x @ w1.T + b1); h2 = relu(h1 @ w2.T + b2); lg = h2 @ w3.T + b3
//   out[b] = concat(softmax(lg[0:2]), softmax(lg[2:6]), softmax(lg[6:10]))
//
// Weights (744 floats) staged into LDS once per block; all lanes read the
// same address (broadcast, conflict-free), via float4 -> ds_read_b128.

#define RCELLS 5

__global__ __launch_bounds__(256) void fused_model_kernel(
    const float* __restrict__ x0,
    const float* __restrict__ xs,
    const float* __restrict__ rnn_w2,
    const float* __restrict__ rnn_b2,
    const float* __restrict__ w1,
    const float* __restrict__ b1,
    const float* __restrict__ w2,
    const float* __restrict__ b2,
    const float* __restrict__ w3,
    const float* __restrict__ b3,
    float* __restrict__ out,
    int B,
    long long sB2,      // S * B * 2   (stride between rnn cells in xs)
    long long lastOff)  // (S-1) * B * 2
{
    // LDS layout (floats), 16B-aligned segments:
    //   [0,256)   w1      [256,512) w2       [512,672) w3
    //   [672,688) b1      [688,704) b2       [704,714) b3
    //   [720,740) rnn_w2  [740,750) rnn_b2
    __shared__ __align__(16) float sm[768];
    const int t = threadIdx.x;

    sm[t]       = w1[t];          // blockDim == 256 exactly
    sm[256 + t] = w2[t];
    if (t < 160) sm[512 + t] = w3[t];
    if (t < 16) { sm[672 + t] = b1[t]; sm[688 + t] = b2[t]; }
    if (t < 20) sm[720 + t] = rnn_w2[t];
    if (t < 10) { sm[704 + t] = b3[t]; sm[740 + t] = rnn_b2[t]; }
    __syncthreads();

    const int b = blockIdx.x * 256 + t;
    if (b >= B) return;

    // ---- build the 16-wide input vector ----
    float x[16];
    {
        const float2* p = reinterpret_cast<const float2*>(x0 + (size_t)b * 6);
        float2 a = p[0], c = p[1], d = p[2];
        x[0] = a.x; x[1] = a.y; x[2] = c.x; x[3] = c.y; x[4] = d.x; x[5] = d.y;
    }
#pragma unroll
    for (int r = 0; r < RCELLS; ++r) {
        const float2 xt = *reinterpret_cast<const float2*>(
            xs + (size_t)r * sB2 + lastOff + (size_t)b * 2);
        const float* rw = sm + 720 + r * 4;  // rnn_w2[r] row-major [2][2]
        const float* rb = sm + 740 + r * 2;
        x[6 + 2 * r] = fmaf(xt.x, rw[0], fmaf(xt.y, rw[1], rb[0]));
        x[7 + 2 * r] = fmaf(xt.x, rw[2], fmaf(xt.y, rw[3], rb[1]));
    }

    const float4* w1v = reinterpret_cast<const float4*>(sm);
    const float4* w2v = reinterpret_cast<const float4*>(sm + 256);
    const float4* w3v = reinterpret_cast<const float4*>(sm + 512);

    // ---- layer 1 ----
    float h1[16];
#pragma unroll
    for (int o = 0; o < 16; ++o) {
        float acc = sm[672 + o];
#pragma unroll
        for (int k = 0; k < 4; ++k) {
            float4 w = w1v[o * 4 + k];
            acc = fmaf(x[4 * k + 0], w.x, acc);
            acc = fmaf(x[4 * k + 1], w.y, acc);
            acc = fmaf(x[4 * k + 2], w.z, acc);
            acc = fmaf(x[4 * k + 3], w.w, acc);
        }
        h1[o] = fmaxf(acc, 0.0f);
    }

    // ---- layer 2 ----
    float h2[16];
#pragma unroll
    for (int o = 0; o < 16; ++o) {
        float acc = sm[688 + o];
#pragma unroll
        for (int k = 0; k < 4; ++k) {
            float4 w = w2v[o * 4 + k];
            acc = fmaf(h1[4 * k + 0], w.x, acc);
            acc = fmaf(h1[4 * k + 1], w.y, acc);
            acc = fmaf(h1[4 * k + 2], w.z, acc);
            acc = fmaf(h1[4 * k + 3], w.w, acc);
        }
        h2[o] = fmaxf(acc, 0.0f);
    }

    // ---- logits ----
    float lg[10];
#pragma unroll
    for (int o = 0; o < 10; ++o) {
        float acc = sm[704 + o];
#pragma unroll
        for (int k = 0; k < 4; ++k) {
            float4 w = w3v[o * 4 + k];
            acc = fmaf(h2[4 * k + 0], w.x, acc);
            acc = fmaf(h2[4 * k + 1], w.y, acc);
            acc = fmaf(h2[4 * k + 2], w.z, acc);
            acc = fmaf(h2[4 * k + 3], w.w, acc);
        }
        lg[o] = acc;
    }

    // ---- grouped softmax: [0:2], [2:6], [6:10] ----
    float p[10];
    {
        float m = fmaxf(lg[0], lg[1]);
        float e0 = __expf(lg[0] - m), e1 = __expf(lg[1] - m);
        float inv = 1.0f / (e0 + e1);
        p[0] = e0 * inv; p[1] = e1 * inv;
    }
    {
        float m = fmaxf(fmaxf(lg[2], lg[3]), fmaxf(lg[4], lg[5]));
        float e2 = __expf(lg[2] - m), e3 = __expf(lg[3] - m);
        float e4 = __expf(lg[4] - m), e5 = __expf(lg[5] - m);
        float inv = 1.0f / (e2 + e3 + e4 + e5);
        p[2] = e2 * inv; p[3] = e3 * inv; p[4] = e4 * inv; p[5] = e5 * inv;
    }
    {
        float m = fmaxf(fmaxf(lg[6], lg[7]), fmaxf(lg[8], lg[9]));
        float e6 = __expf(lg[6] - m), e7 = __expf(lg[7] - m);
        float e8 = __expf(lg[8] - m), e9 = __expf(lg[9] - m);
        float inv = 1.0f / (e6 + e7 + e8 + e9);
        p[6] = e6 * inv; p[7] = e7 * inv; p[8] = e8 * inv; p[9] = e9 * inv;
    }

    // ---- store (b*10 floats = 40B, 8B-aligned -> 5x float2) ----
    float2* po = reinterpret_cast<float2*>(out + (size_t)b * 10);
    po[0] = make_float2(p[0], p[1]);
    po[1] = make_float2(p[2], p[3]);
    po[2] = make_float2(p[4], p[5]);
    po[3] = make_float2(p[6], p[7]);
    po[4] = make_float2(p[8], p[9]);
}

extern "C" void kernel_launch(void* const* d_in, const int* in_sizes, int n_in,
                              void* d_out, int out_size, void* d_ws, size_t ws_size,
                              hipStream_t stream) {
    const float* x0     = (const float*)d_in[0];
    const float* xs     = (const float*)d_in[1];
    // d_in[2] = rnn_w1, d_in[3] = rnn_b1 -- dead code in the reference (DCE'd)
    const float* rnn_w2 = (const float*)d_in[4];
    const float* rnn_b2 = (const float*)d_in[5];
    const float* w1     = (const float*)d_in[6];
    const float* b1     = (const float*)d_in[7];
    const float* w2     = (const float*)d_in[8];
    const float* b2     = (const float*)d_in[9];
    const float* w3     = (const float*)d_in[10];
    const float* b3     = (const float*)d_in[11];

    const int B = in_sizes[0] / 6;                    // x0 is [B, 6]
    const int S = in_sizes[1] / (RCELLS * 2 * B);     // xs is [R, S, B, 2]
    const long long sB2     = (long long)S * B * 2;
    const long long lastOff = (long long)(S - 1) * B * 2;

    const int grid = (B + 255) / 256;
    fused_model_kernel<<<grid, 256, 0, stream>>>(
        x0, xs, rnn_w2, rnn_b2, w1, b1, w2, b2, w3, b3,
        (float*)d_out, B, sB2, lastOff);
}